// Round 1
// baseline (372.330 us; speedup 1.0000x reference)
//
#include <hip/hip_runtime.h>
#include <math.h>

#define B_ 4
#define C_ 64
#define L_ 4096
#define DM 128
#define DI 256
#define DS 16

// ---------------------------------------------------------------- helpers
__device__ __forceinline__ float silu_f(float v) {
    return v / (1.0f + __expf(-v));
}

// ---------------------------------------------------------------- A = -exp(A_log)
__global__ void k_negexp(const float* __restrict__ A_log, float* __restrict__ A, int n) {
    int i = blockIdx.x * 256 + threadIdx.x;
    if (i < n) A[i] = -__expf(A_log[i]);
}

// ---------------------------------------------------------------- proj (64->128) + LayerNorm
// 4 threads per (b,l) row, each owns 32 of the 128 outputs.
__global__ __launch_bounds__(256) void k_proj_ln(
    const float* __restrict__ x, const float* __restrict__ pw,
    const float* __restrict__ pb, const float* __restrict__ g,
    const float* __restrict__ bta, float* __restrict__ xm)
{
    int t = blockIdx.x * 256 + threadIdx.x;
    int row = t >> 2;            // b*L + l
    int q = t & 3;
    int b = row >> 12;
    int l = row & 4095;
    const float* xb = x + (size_t)b * C_ * L_ + l;

    float acc[32];
#pragma unroll
    for (int j = 0; j < 32; ++j) acc[j] = 0.f;

    for (int c = 0; c < C_; ++c) {
        float xv = xb[(size_t)c * L_];
        const float4* wr = (const float4*)(pw + c * DM + q * 32);
#pragma unroll
        for (int j4 = 0; j4 < 8; ++j4) {
            float4 w = wr[j4];
            acc[j4 * 4 + 0] += xv * w.x;
            acc[j4 * 4 + 1] += xv * w.y;
            acc[j4 * 4 + 2] += xv * w.z;
            acc[j4 * 4 + 3] += xv * w.w;
        }
    }
    float s = 0.f;
#pragma unroll
    for (int j = 0; j < 32; ++j) { acc[j] += pb[q * 32 + j]; s += acc[j]; }
    s += __shfl_xor(s, 1);
    s += __shfl_xor(s, 2);
    float mu = s * (1.0f / 128.0f);
    float s2 = 0.f;
#pragma unroll
    for (int j = 0; j < 32; ++j) { float dv = acc[j] - mu; s2 += dv * dv; }
    s2 += __shfl_xor(s2, 1);
    s2 += __shfl_xor(s2, 2);
    float inv = rsqrtf(s2 * (1.0f / 128.0f) + 1e-5f);
    float* o = xm + (size_t)row * DM + q * 32;
#pragma unroll
    for (int j = 0; j < 32; ++j)
        o[j] = (acc[j] - mu) * inv * g[q * 32 + j] + bta[q * 32 + j];
}

// ---------------------------------------------------------------- generic 64x64-tile fp32 GEMM
__global__ __launch_bounds__(256) void k_gemm64(
    const float* __restrict__ A, const float* __restrict__ Bw,
    float* __restrict__ Cm, int M, int N, int K)
{
    __shared__ float As[64][65];
    __shared__ float Bs[64][65];
    int row0 = blockIdx.y * 64, col0 = blockIdx.x * 64;
    int t = threadIdx.x;
    int ty = t >> 4, tx = t & 15;
    float acc[4][4] = {};
    for (int k0 = 0; k0 < K; k0 += 64) {
#pragma unroll
        for (int i = 0; i < 4; ++i) {
            int r = (t >> 4) + i * 16;
            int c = (t & 15) * 4;
            float4 v = *(const float4*)(A + (size_t)(row0 + r) * K + k0 + c);
            As[r][c] = v.x; As[r][c + 1] = v.y; As[r][c + 2] = v.z; As[r][c + 3] = v.w;
        }
#pragma unroll
        for (int i = 0; i < 4; ++i) {
            int r = (t >> 4) + i * 16;
            int c = (t & 15) * 4;
            float4 v = *(const float4*)(Bw + (size_t)(k0 + r) * N + col0 + c);
            Bs[r][c] = v.x; Bs[r][c + 1] = v.y; Bs[r][c + 2] = v.z; Bs[r][c + 3] = v.w;
        }
        __syncthreads();
#pragma unroll
        for (int kk = 0; kk < 64; ++kk) {
            float a[4], bv[4];
#pragma unroll
            for (int i = 0; i < 4; ++i) a[i] = As[ty * 4 + i][kk];
#pragma unroll
            for (int j = 0; j < 4; ++j) bv[j] = Bs[kk][tx * 4 + j];
#pragma unroll
            for (int i = 0; i < 4; ++i)
#pragma unroll
                for (int j = 0; j < 4; ++j)
                    acc[i][j] += a[i] * bv[j];
        }
        __syncthreads();
    }
#pragma unroll
    for (int i = 0; i < 4; ++i) {
        float4 v = make_float4(acc[i][0], acc[i][1], acc[i][2], acc[i][3]);
        *(float4*)(Cm + (size_t)(row0 + ty * 4 + i) * N + col0 + tx * 4) = v;
    }
}

// ---------------------------------------------------------------- depthwise causal conv (K=4) + SiLU
__global__ __launch_bounds__(256) void k_conv(
    const float* __restrict__ xz, const float* __restrict__ cw,
    const float* __restrict__ cb, float* __restrict__ u)
{
    int idx = blockIdx.x * 256 + threadIdx.x;  // over B*L*DI
    int d = idx & 255;
    int l = (idx >> 8) & 4095;
    int b = idx >> 20;
    float4 w = ((const float4*)cw)[d];
    float s = cb[d];
    size_t rowbase = ((size_t)(b << 12)) * 512 + d;
    if (l >= 3) s += xz[rowbase + (size_t)(l - 3) * 512] * w.x;
    if (l >= 2) s += xz[rowbase + (size_t)(l - 2) * 512] * w.y;
    if (l >= 1) s += xz[rowbase + (size_t)(l - 1) * 512] * w.z;
    s += xz[rowbase + (size_t)l * 512] * w.w;
    u[idx] = silu_f(s);
}

// ---------------------------------------------------------------- x_proj (256->40) + dt_proj (8->256) + softplus
// one block per (b, 64-row chunk)
__global__ __launch_bounds__(256) void k_xproj_dt(
    const float* __restrict__ u, const float* __restrict__ xpw,
    const float* __restrict__ dtw, const float* __restrict__ dtb,
    float* __restrict__ dt, float* __restrict__ Bc, float* __restrict__ Cc)
{
    __shared__ float u_s[64][65];
    __shared__ float w_s[64][40];
    __shared__ float x_s[64][40];
    int blk = blockIdx.x;          // b*64 + ch
    int b = blk >> 6;
    int l0 = (blk & 63) * 64;
    int t = threadIdx.x;
    int tl = t >> 2, jq = t & 3;
    float acc[10] = {};
    const float* ub = u + ((size_t)(b << 12) + l0) * DI;

    for (int k0 = 0; k0 < DI; k0 += 64) {
#pragma unroll
        for (int i = 0; i < 4; ++i) {
            int r = (t >> 4) + i * 16;
            int c = (t & 15) * 4;
            float4 v = *(const float4*)(ub + (size_t)r * DI + k0 + c);
            u_s[r][c] = v.x; u_s[r][c + 1] = v.y; u_s[r][c + 2] = v.z; u_s[r][c + 3] = v.w;
        }
        for (int i = t; i < 64 * 40; i += 256) {
            int r = i / 40, c = i % 40;
            w_s[r][c] = xpw[(size_t)(k0 + r) * 40 + c];
        }
        __syncthreads();
#pragma unroll
        for (int k = 0; k < 64; ++k) {
            float uv = u_s[tl][k];
#pragma unroll
            for (int j = 0; j < 10; ++j) acc[j] += uv * w_s[k][jq * 10 + j];
        }
        __syncthreads();
    }
#pragma unroll
    for (int j = 0; j < 10; ++j) x_s[tl][jq * 10 + j] = acc[j];
    __syncthreads();

    // write B, C slices
    for (int i = t; i < 64 * 16; i += 256) {
        int l = i >> 4, n = i & 15;
        size_t o = ((size_t)(b << 12) + l0 + l) * 16 + n;
        Bc[o] = x_s[l][8 + n];
        Cc[o] = x_s[l][24 + n];
    }
    // dt = softplus(x_s[:, :8] @ dtw + dtb), thread = d
    int d = t;
    float wv[8];
#pragma unroll
    for (int r = 0; r < 8; ++r) wv[r] = dtw[r * DI + d];
    float bias = dtb[d];
    for (int l = 0; l < 64; ++l) {
        float s = bias;
#pragma unroll
        for (int r = 0; r < 8; ++r) s += x_s[l][r] * wv[r];
        float sp = (s > 20.f) ? s : log1pf(__expf(s));
        dt[((size_t)(b << 12) + l0 + l) * DI + d] = sp;
    }
}

// ---------------------------------------------------------------- scan pass 1: chunk summaries (P, S)
__global__ __launch_bounds__(256) void k_scan1(
    const float* __restrict__ dt, const float* __restrict__ u,
    const float* __restrict__ Bc, const float* __restrict__ A,
    float* __restrict__ Pg, float* __restrict__ Sg)
{
    __shared__ float Bs[64][16];
    int blk = blockIdx.x;
    int b = blk >> 6, ch = blk & 63;
    int l0 = ch * 64;
    int t = threadIdx.x;  // = d
    for (int i = t; i < 64 * 16; i += 256)
        Bs[i >> 4][i & 15] = Bc[((size_t)(b << 12) + l0 + (i >> 4)) * 16 + (i & 15)];
    __syncthreads();

    float av[16];
#pragma unroll
    for (int n = 0; n < 16; ++n) av[n] = A[t * 16 + n];
    float S[16] = {};
    float dts = 0.f;
    const float* dtp = dt + ((size_t)(b << 12) + l0) * DI + t;
    const float* up  = u  + ((size_t)(b << 12) + l0) * DI + t;
    for (int l = 0; l < 64; ++l) {
        float dtv = dtp[(size_t)l * DI];
        float uv  = up[(size_t)l * DI];
        float t1 = dtv * uv;
        dts += dtv;
#pragma unroll
        for (int n = 0; n < 16; ++n) {
            float dA = __expf(av[n] * dtv);
            S[n] = dA * S[n] + t1 * Bs[l][n];
        }
    }
    size_t o = ((size_t)blk * 256 + t) * 16;
#pragma unroll
    for (int n = 0; n < 16; ++n) {
        Pg[o + n] = __expf(av[n] * dts);
        Sg[o + n] = S[n];
    }
}

// ---------------------------------------------------------------- scan pass 2: scan over chunks
// block = (b, group of 16 d); thread = (d_local, n). Fully coalesced.
__global__ __launch_bounds__(256) void k_scan2(
    const float* __restrict__ Pg, const float* __restrict__ Sg,
    float* __restrict__ h0)
{
    int blk = blockIdx.x;       // b*16 + dg
    int b = blk >> 4, dg = blk & 15;
    int t = threadIdx.x;
    size_t stride = 4096;       // 256*16 floats per chunk
    size_t base0 = ((size_t)b * 64) * stride + (size_t)dg * 256 + t;
    float h = 0.f;
    for (int cb = 0; cb < 8; ++cb) {
        float P[8], S[8];
#pragma unroll
        for (int j = 0; j < 8; ++j) {
            size_t o = base0 + (size_t)(cb * 8 + j) * stride;
            P[j] = Pg[o]; S[j] = Sg[o];
        }
#pragma unroll
        for (int j = 0; j < 8; ++j) {
            size_t o = base0 + (size_t)(cb * 8 + j) * stride;
            h0[o] = h;
            h = P[j] * h + S[j];
        }
    }
}

// ---------------------------------------------------------------- scan pass 3: recurrence + y + gating
__global__ __launch_bounds__(256) void k_scan3(
    const float* __restrict__ dt, const float* __restrict__ u,
    const float* __restrict__ Bc, const float* __restrict__ Cc,
    const float* __restrict__ xz, const float* __restrict__ A,
    const float* __restrict__ h0, const float* __restrict__ Dp,
    float* __restrict__ y)
{
    __shared__ float Bs[64][16];
    __shared__ float Cs[64][16];
    int blk = blockIdx.x;
    int b = blk >> 6, ch = blk & 63;
    int l0 = ch * 64;
    int t = threadIdx.x;  // = d
    for (int i = t; i < 64 * 16; i += 256) {
        int l = i >> 4, n = i & 15;
        size_t o = ((size_t)(b << 12) + l0 + l) * 16 + n;
        Bs[l][n] = Bc[o];
        Cs[l][n] = Cc[o];
    }
    __syncthreads();

    float av[16], h[16];
#pragma unroll
    for (int n = 0; n < 16; ++n) av[n] = A[t * 16 + n];
    size_t hb = ((size_t)blk * 256 + t) * 16;
#pragma unroll
    for (int n = 0; n < 16; ++n) h[n] = h0[hb + n];
    float Dd = Dp[t];
    const float* dtp = dt + ((size_t)(b << 12) + l0) * DI + t;
    const float* up  = u  + ((size_t)(b << 12) + l0) * DI + t;
    const float* zp  = xz + ((size_t)(b << 12) + l0) * 512 + 256 + t;
    float* yp = y + ((size_t)(b << 12) + l0) * DI + t;
    for (int l = 0; l < 64; ++l) {
        float dtv = dtp[(size_t)l * DI];
        float uv  = up[(size_t)l * DI];
        float zv  = zp[(size_t)l * 512];
        float t1 = dtv * uv;
        float acc = 0.f;
#pragma unroll
        for (int n = 0; n < 16; ++n) {
            float dA = __expf(av[n] * dtv);
            h[n] = dA * h[n] + t1 * Bs[l][n];
            acc += h[n] * Cs[l][n];
        }
        float yv = acc + uv * Dd;
        yv *= silu_f(zv);
        yp[(size_t)l * DI] = yv;
    }
}

// ---------------------------------------------------------------- proj_out (128->64) + bias + residual + NCHW store
__global__ __launch_bounds__(256) void k_projout_res(
    const float* __restrict__ xm2, const float* __restrict__ pw,
    const float* __restrict__ pb, const float* __restrict__ x,
    float* __restrict__ out)
{
    __shared__ float As[64][65];
    __shared__ float Bs[64][65];
    __shared__ float Ts[64][65];
    int blk = blockIdx.x;  // b*64 + lt
    int b = blk >> 6, lt = blk & 63;
    int l0 = lt * 64;
    int t = threadIdx.x, ty = t >> 4, tx = t & 15;
    float acc[4][4] = {};
    const float* Ab = xm2 + ((size_t)(b << 12) + l0) * DM;
    for (int k0 = 0; k0 < DM; k0 += 64) {
#pragma unroll
        for (int i = 0; i < 4; ++i) {
            int r = (t >> 4) + i * 16;
            int c = (t & 15) * 4;
            float4 v = *(const float4*)(Ab + (size_t)r * DM + k0 + c);
            As[r][c] = v.x; As[r][c + 1] = v.y; As[r][c + 2] = v.z; As[r][c + 3] = v.w;
        }
#pragma unroll
        for (int i = 0; i < 4; ++i) {
            int r = (t >> 4) + i * 16;
            int c = (t & 15) * 4;
            float4 v = *(const float4*)(pw + (size_t)(k0 + r) * 64 + c);
            Bs[r][c] = v.x; Bs[r][c + 1] = v.y; Bs[r][c + 2] = v.z; Bs[r][c + 3] = v.w;
        }
        __syncthreads();
#pragma unroll
        for (int kk = 0; kk < 64; ++kk) {
            float a[4], bv[4];
#pragma unroll
            for (int i = 0; i < 4; ++i) a[i] = As[ty * 4 + i][kk];
#pragma unroll
            for (int j = 0; j < 4; ++j) bv[j] = Bs[kk][tx * 4 + j];
#pragma unroll
            for (int i = 0; i < 4; ++i)
#pragma unroll
                for (int j = 0; j < 4; ++j)
                    acc[i][j] += a[i] * bv[j];
        }
        __syncthreads();
    }
#pragma unroll
    for (int i = 0; i < 4; ++i)
#pragma unroll
        for (int j = 0; j < 4; ++j)
            Ts[ty * 4 + i][tx * 4 + j] = acc[i][j] + pb[tx * 4 + j];
    __syncthreads();
    for (int i = t; i < 4096; i += 256) {
        int c = i >> 6, l = i & 63;
        size_t o = ((size_t)b * 64 + c) * 4096 + l0 + l;
        out[o] = x[o] + Ts[l][c];
    }
}

// ---------------------------------------------------------------- launch
extern "C" void kernel_launch(void* const* d_in, const int* in_sizes, int n_in,
                              void* d_out, int out_size, void* d_ws, size_t ws_size,
                              hipStream_t stream)
{
    (void)in_sizes; (void)n_in; (void)out_size; (void)ws_size;
    const float* x          = (const float*)d_in[0];
    const float* proj_w     = (const float*)d_in[1];
    const float* proj_b     = (const float*)d_in[2];
    const float* ln_g       = (const float*)d_in[3];
    const float* ln_b       = (const float*)d_in[4];
    const float* in_proj_w  = (const float*)d_in[5];
    const float* conv_w     = (const float*)d_in[6];
    const float* conv_b     = (const float*)d_in[7];
    const float* x_proj_w   = (const float*)d_in[8];
    const float* dt_proj_w  = (const float*)d_in[9];
    const float* dt_proj_b  = (const float*)d_in[10];
    const float* A_log      = (const float*)d_in[11];
    const float* Dp         = (const float*)d_in[12];
    const float* out_proj_w = (const float*)d_in[13];
    const float* proj_out_w = (const float*)d_in[14];
    const float* proj_out_b = (const float*)d_in[15];
    float* out = (float*)d_out;

    float* ws  = (float*)d_ws;
    float* A    = ws;                 // 4096
    float* xm   = A   + 4096;         // 2,097,152
    float* xz   = xm  + 2097152;      // 8,388,608
    float* u    = xz  + 8388608;      // 4,194,304
    float* dtg  = u   + 4194304;      // 4,194,304
    float* Bc   = dtg + 4194304;      // 262,144
    float* Cc   = Bc  + 262144;       // 262,144
    float* Pg   = Cc  + 262144;       // 1,048,576
    float* Sg   = Pg  + 1048576;      // 1,048,576
    float* h0   = Sg  + 1048576;      // 1,048,576
    float* yb   = h0  + 1048576;      // 4,194,304
    float* xm2  = yb  + 4194304;      // 2,097,152

    k_negexp<<<16, 256, 0, stream>>>(A_log, A, 4096);
    k_proj_ln<<<256, 256, 0, stream>>>(x, proj_w, proj_b, ln_g, ln_b, xm);
    k_gemm64<<<dim3(8, 256), 256, 0, stream>>>(xm, in_proj_w, xz, 16384, 512, 128);
    k_conv<<<16384, 256, 0, stream>>>(xz, conv_w, conv_b, u);
    k_xproj_dt<<<256, 256, 0, stream>>>(u, x_proj_w, dt_proj_w, dt_proj_b, dtg, Bc, Cc);
    k_scan1<<<256, 256, 0, stream>>>(dtg, u, Bc, A, Pg, Sg);
    k_scan2<<<64, 256, 0, stream>>>(Pg, Sg, h0);
    k_scan3<<<256, 256, 0, stream>>>(dtg, u, Bc, Cc, xz, A, h0, Dp, yb);
    k_gemm64<<<dim3(2, 256), 256, 0, stream>>>(yb, out_proj_w, xm2, 16384, 128, 256);
    k_projout_res<<<256, 256, 0, stream>>>(xm2, proj_out_w, proj_out_b, x, out);
}

// Round 2
// 324.788 us; speedup vs baseline: 1.1464x; 1.1464x over previous
//
#include <hip/hip_runtime.h>
#include <hip/hip_bf16.h>
#include <math.h>

#define B_ 4
#define C_ 64
#define L_ 4096
#define DM 128
#define DI 256
#define DS 16

typedef __attribute__((ext_vector_type(8))) short short8v;
typedef __attribute__((ext_vector_type(4))) float f32x4;

__device__ __forceinline__ float silu_f(float v) {
    return v / (1.0f + __expf(-v));
}

// ---------------------------------------------------------------- prep:
// blocks 0..15 : Wt[n][k] = bf16(in_proj_w[k][n])   (512x128)
// blocks 16..79: W2t[c][r] = bf16(sum_k out_proj_w[r][k]*proj_out_w[k][c])
__global__ __launch_bounds__(256) void k_prep(
    const float* __restrict__ ipw, const float* __restrict__ opw,
    const float* __restrict__ pow_, __hip_bfloat16* __restrict__ Wt,
    __hip_bfloat16* __restrict__ W2t)
{
    __shared__ float pls[128][65];
    int blk = blockIdx.x, t = threadIdx.x;
    if (blk < 16) {
        for (int it = 0; it < 16; ++it) {
            int e = blk * 4096 + it * 256 + t;
            int n = e >> 7, k = e & 127;
            Wt[e] = __float2bfloat16(ipw[k * 512 + n]);
        }
    } else {
        for (int i = t; i < 8192; i += 256)
            pls[i >> 6][i & 63] = pow_[i];
        __syncthreads();
        int o = (blk - 16) * 256 + t;
        int r = o >> 6, c = o & 63;
        float acc = 0.f;
        for (int k = 0; k < 128; ++k)
            acc += opw[r * 128 + k] * pls[k][c];
        W2t[c * 256 + r] = __float2bfloat16(acc);
    }
}

// ---------------------------------------------------------------- proj (64->128) + LayerNorm -> bf16
// block: one b, 64 rows. x tile staged in LDS (coalesced), 4 threads/row.
__global__ __launch_bounds__(256) void k_proj_ln(
    const float* __restrict__ x, const float* __restrict__ pw,
    const float* __restrict__ pb, const float* __restrict__ g,
    const float* __restrict__ bta, __hip_bfloat16* __restrict__ xmb)
{
    __shared__ float xs[64][65];   // [c][l]
    int blk = blockIdx.x;          // b*64 + lt
    int b = blk >> 6;
    int l0 = (blk & 63) * 64;
    int t = threadIdx.x;

    // stage x[b, 0..63, l0..l0+63] coalesced
#pragma unroll
    for (int it = 0; it < 4; ++it) {
        int i = t + it * 256;
        int c = i >> 4, lq = (i & 15) * 4;
        float4 v = *(const float4*)&x[(((size_t)b * 64 + c) << 12) + l0 + lq];
        xs[c][lq] = v.x; xs[c][lq + 1] = v.y; xs[c][lq + 2] = v.z; xs[c][lq + 3] = v.w;
    }
    __syncthreads();

    int row = t >> 2;   // 0..63
    int q = t & 3;
    float acc[32];
#pragma unroll
    for (int j = 0; j < 32; ++j) acc[j] = 0.f;
    for (int c = 0; c < 64; ++c) {
        float xv = xs[c][row];
        const float4* wr4 = (const float4*)(pw + c * DM + q * 32);
#pragma unroll
        for (int j4 = 0; j4 < 8; ++j4) {
            float4 w = wr4[j4];
            acc[j4 * 4 + 0] += xv * w.x;
            acc[j4 * 4 + 1] += xv * w.y;
            acc[j4 * 4 + 2] += xv * w.z;
            acc[j4 * 4 + 3] += xv * w.w;
        }
    }
    float s = 0.f;
#pragma unroll
    for (int j = 0; j < 32; ++j) { acc[j] += pb[q * 32 + j]; s += acc[j]; }
    s += __shfl_xor(s, 1);
    s += __shfl_xor(s, 2);
    float mu = s * (1.0f / 128.0f);
    float s2 = 0.f;
#pragma unroll
    for (int j = 0; j < 32; ++j) { float dv = acc[j] - mu; s2 += dv * dv; }
    s2 += __shfl_xor(s2, 1);
    s2 += __shfl_xor(s2, 2);
    float inv = rsqrtf(s2 * (1.0f / 128.0f) + 1e-5f);
    size_t ob = ((size_t)(b << 12) + l0 + row) * DM + q * 32;
#pragma unroll
    for (int j = 0; j < 32; ++j)
        xmb[ob + j] = __float2bfloat16((acc[j] - mu) * inv * g[q * 32 + j] + bta[q * 32 + j]);
}

// ---------------------------------------------------------------- in_proj MFMA: xz = xm @ W  (16384x512, K=128)
// LDS-free: frags straight from L1/L2. 128x128 tile, 4 waves, 64x64/wave.
__global__ __launch_bounds__(256) void k_gemm_in(
    const __hip_bfloat16* __restrict__ xmb, const __hip_bfloat16* __restrict__ Wt,
    float* __restrict__ xz)
{
    int n0 = blockIdx.x * 128, m0 = blockIdx.y * 128;
    int t = threadIdx.x;
    int w = t >> 6, lane = t & 63;
    int wr = w >> 1, wc = w & 1;
    int lr = lane & 15, lg = lane >> 4;
    const short* X = (const short*)xmb;
    const short* Wp = (const short*)Wt;
    f32x4 acc[4][4] = {};
#pragma unroll
    for (int kk = 0; kk < 4; ++kk) {
        int k0 = kk * 32;
        short8v a[4], b[4];
#pragma unroll
        for (int m = 0; m < 4; ++m)
            a[m] = *(const short8v*)&X[(size_t)(m0 + wr * 64 + m * 16 + lr) * 128 + k0 + lg * 8];
#pragma unroll
        for (int n = 0; n < 4; ++n)
            b[n] = *(const short8v*)&Wp[(size_t)(n0 + wc * 64 + n * 16 + lr) * 128 + k0 + lg * 8];
#pragma unroll
        for (int m = 0; m < 4; ++m)
#pragma unroll
            for (int n = 0; n < 4; ++n)
                acc[m][n] = __builtin_amdgcn_mfma_f32_16x16x32_bf16(a[m], b[n], acc[m][n], 0, 0, 0);
    }
#pragma unroll
    for (int m = 0; m < 4; ++m)
#pragma unroll
        for (int n = 0; n < 4; ++n)
#pragma unroll
            for (int r = 0; r < 4; ++r)
                xz[(size_t)(m0 + wr * 64 + m * 16 + lg * 4 + r) * 512 + n0 + wc * 64 + n * 16 + lr]
                    = acc[m][n][r];
}

// ---------------------------------------------------------------- depthwise causal conv (K=4) + SiLU
__global__ __launch_bounds__(256) void k_conv(
    const float* __restrict__ xz, const float* __restrict__ cw,
    const float* __restrict__ cb, float* __restrict__ u)
{
    int idx = blockIdx.x * 256 + threadIdx.x;  // over B*L*DI
    int d = idx & 255;
    int l = (idx >> 8) & 4095;
    int b = idx >> 20;
    float4 w = ((const float4*)cw)[d];
    float s = cb[d];
    size_t rowbase = ((size_t)(b << 12)) * 512 + d;
    if (l >= 3) s += xz[rowbase + (size_t)(l - 3) * 512] * w.x;
    if (l >= 2) s += xz[rowbase + (size_t)(l - 2) * 512] * w.y;
    if (l >= 1) s += xz[rowbase + (size_t)(l - 1) * 512] * w.z;
    s += xz[rowbase + (size_t)l * 512] * w.w;
    u[idx] = silu_f(s);
}

// ---------------------------------------------------------------- x_proj (256->40) + dt_proj (8->256) + softplus
__global__ __launch_bounds__(256) void k_xproj_dt(
    const float* __restrict__ u, const float* __restrict__ xpw,
    const float* __restrict__ dtw, const float* __restrict__ dtb,
    float* __restrict__ dt, float* __restrict__ Bc, float* __restrict__ Cc)
{
    __shared__ float u_s[64][65];
    __shared__ float w_s[64][40];
    __shared__ float x_s[64][40];
    int blk = blockIdx.x;          // b*64 + ch
    int b = blk >> 6;
    int l0 = (blk & 63) * 64;
    int t = threadIdx.x;
    int tl = t >> 2, jq = t & 3;
    float acc[10] = {};
    const float* ub = u + ((size_t)(b << 12) + l0) * DI;

    for (int k0 = 0; k0 < DI; k0 += 64) {
#pragma unroll
        for (int i = 0; i < 4; ++i) {
            int r = (t >> 4) + i * 16;
            int c = (t & 15) * 4;
            float4 v = *(const float4*)(ub + (size_t)r * DI + k0 + c);
            u_s[r][c] = v.x; u_s[r][c + 1] = v.y; u_s[r][c + 2] = v.z; u_s[r][c + 3] = v.w;
        }
        for (int i = t; i < 64 * 40; i += 256) {
            int r = i / 40, c = i % 40;
            w_s[r][c] = xpw[(size_t)(k0 + r) * 40 + c];
        }
        __syncthreads();
#pragma unroll
        for (int k = 0; k < 64; ++k) {
            float uv = u_s[tl][k];
#pragma unroll
            for (int j = 0; j < 10; ++j) acc[j] += uv * w_s[k][jq * 10 + j];
        }
        __syncthreads();
    }
#pragma unroll
    for (int j = 0; j < 10; ++j) x_s[tl][jq * 10 + j] = acc[j];
    __syncthreads();

    for (int i = t; i < 64 * 16; i += 256) {
        int l = i >> 4, n = i & 15;
        size_t o = ((size_t)(b << 12) + l0 + l) * 16 + n;
        Bc[o] = x_s[l][8 + n];
        Cc[o] = x_s[l][24 + n];
    }
    int d = t;
    float wv[8];
#pragma unroll
    for (int r = 0; r < 8; ++r) wv[r] = dtw[r * DI + d];
    float bias = dtb[d];
    for (int l = 0; l < 64; ++l) {
        float s = bias;
#pragma unroll
        for (int r = 0; r < 8; ++r) s += x_s[l][r] * wv[r];
        float sp = (s > 20.f) ? s : log1pf(__expf(s));
        dt[((size_t)(b << 12) + l0 + l) * DI + d] = sp;
    }
}

// ---------------------------------------------------------------- scan pass 1: chunk summaries (P, S)
__global__ __launch_bounds__(256) void k_scan1(
    const float* __restrict__ dt, const float* __restrict__ u,
    const float* __restrict__ Bc, const float* __restrict__ A_log,
    float* __restrict__ Pg, float* __restrict__ Sg)
{
    __shared__ float Bs[64][16];
    int blk = blockIdx.x;
    int b = blk >> 6, ch = blk & 63;
    int l0 = ch * 64;
    int t = threadIdx.x;  // = d
    for (int i = t; i < 64 * 16; i += 256)
        Bs[i >> 4][i & 15] = Bc[((size_t)(b << 12) + l0 + (i >> 4)) * 16 + (i & 15)];
    __syncthreads();

    float av[16];
    const float4* Ap = (const float4*)(A_log + t * 16);
#pragma unroll
    for (int j4 = 0; j4 < 4; ++j4) {
        float4 v = Ap[j4];
        av[j4 * 4 + 0] = -__expf(v.x);
        av[j4 * 4 + 1] = -__expf(v.y);
        av[j4 * 4 + 2] = -__expf(v.z);
        av[j4 * 4 + 3] = -__expf(v.w);
    }
    float S[16] = {};
    float dts = 0.f;
    const float* dtp = dt + ((size_t)(b << 12) + l0) * DI + t;
    const float* up  = u  + ((size_t)(b << 12) + l0) * DI + t;
    for (int l = 0; l < 64; ++l) {
        float dtv = dtp[(size_t)l * DI];
        float uv  = up[(size_t)l * DI];
        float t1 = dtv * uv;
        dts += dtv;
#pragma unroll
        for (int n = 0; n < 16; ++n) {
            float dA = __expf(av[n] * dtv);
            S[n] = dA * S[n] + t1 * Bs[l][n];
        }
    }
    size_t o = ((size_t)blk * 256 + t) * 16;
#pragma unroll
    for (int n = 0; n < 16; ++n) {
        Pg[o + n] = __expf(av[n] * dts);
        Sg[o + n] = S[n];
    }
}

// ---------------------------------------------------------------- scan pass 2: scan over chunks
__global__ __launch_bounds__(256) void k_scan2(
    const float* __restrict__ Pg, const float* __restrict__ Sg,
    float* __restrict__ h0)
{
    int blk = blockIdx.x;       // b*16 + dg
    int b = blk >> 4, dg = blk & 15;
    int t = threadIdx.x;
    size_t stride = 4096;       // 256*16 floats per chunk
    size_t base0 = ((size_t)b * 64) * stride + (size_t)dg * 256 + t;
    float h = 0.f;
    for (int cb = 0; cb < 8; ++cb) {
        float P[8], S[8];
#pragma unroll
        for (int j = 0; j < 8; ++j) {
            size_t o = base0 + (size_t)(cb * 8 + j) * stride;
            P[j] = Pg[o]; S[j] = Sg[o];
        }
#pragma unroll
        for (int j = 0; j < 8; ++j) {
            size_t o = base0 + (size_t)(cb * 8 + j) * stride;
            h0[o] = h;
            h = P[j] * h + S[j];
        }
    }
}

// ---------------------------------------------------------------- scan pass 3: recurrence + y + gating -> bf16
__global__ __launch_bounds__(256) void k_scan3(
    const float* __restrict__ dt, const float* __restrict__ u,
    const float* __restrict__ Bc, const float* __restrict__ Cc,
    const float* __restrict__ xz, const float* __restrict__ A_log,
    const float* __restrict__ h0, const float* __restrict__ Dp,
    __hip_bfloat16* __restrict__ yb)
{
    __shared__ float Bs[64][16];
    __shared__ float Cs[64][16];
    int blk = blockIdx.x;
    int b = blk >> 6, ch = blk & 63;
    int l0 = ch * 64;
    int t = threadIdx.x;  // = d
    for (int i = t; i < 64 * 16; i += 256) {
        int l = i >> 4, n = i & 15;
        size_t o = ((size_t)(b << 12) + l0 + l) * 16 + n;
        Bs[l][n] = Bc[o];
        Cs[l][n] = Cc[o];
    }
    __syncthreads();

    float av[16], h[16];
    const float4* Ap = (const float4*)(A_log + t * 16);
#pragma unroll
    for (int j4 = 0; j4 < 4; ++j4) {
        float4 v = Ap[j4];
        av[j4 * 4 + 0] = -__expf(v.x);
        av[j4 * 4 + 1] = -__expf(v.y);
        av[j4 * 4 + 2] = -__expf(v.z);
        av[j4 * 4 + 3] = -__expf(v.w);
    }
    size_t hb = ((size_t)blk * 256 + t) * 16;
#pragma unroll
    for (int n = 0; n < 16; ++n) h[n] = h0[hb + n];
    float Dd = Dp[t];
    const float* dtp = dt + ((size_t)(b << 12) + l0) * DI + t;
    const float* up  = u  + ((size_t)(b << 12) + l0) * DI + t;
    const float* zp  = xz + ((size_t)(b << 12) + l0) * 512 + 256 + t;
    __hip_bfloat16* yp = yb + ((size_t)(b << 12) + l0) * DI + t;
    for (int l = 0; l < 64; ++l) {
        float dtv = dtp[(size_t)l * DI];
        float uv  = up[(size_t)l * DI];
        float zv  = zp[(size_t)l * 512];
        float t1 = dtv * uv;
        float acc = 0.f;
#pragma unroll
        for (int n = 0; n < 16; ++n) {
            float dA = __expf(av[n] * dtv);
            h[n] = dA * h[n] + t1 * Bs[l][n];
            acc += h[n] * Cs[l][n];
        }
        float yv = (acc + uv * Dd) * silu_f(zv);
        yp[(size_t)l * DI] = __float2bfloat16(yv);
    }
}

// ---------------------------------------------------------------- final MFMA: (y @ W2) + pob + x -> out (NCHW)
// 64 rows/block, 4 waves (16 rows each), K=256, LDS-free frags, LDS transpose store.
__global__ __launch_bounds__(256) void k_gemm_out(
    const __hip_bfloat16* __restrict__ yb, const __hip_bfloat16* __restrict__ W2t,
    const float* __restrict__ pob, const float* __restrict__ x,
    float* __restrict__ out)
{
    __shared__ float Ts[64][65];
    int blk = blockIdx.x;       // rows blk*64..+63
    int t = threadIdx.x;
    int w = t >> 6, lane = t & 63;
    int lr = lane & 15, lg = lane >> 4;
    int row0 = blk * 64;
    const short* Y = (const short*)yb;
    const short* W = (const short*)W2t;
    f32x4 acc[4] = {};
    int arow = row0 + w * 16 + lr;
#pragma unroll
    for (int kk = 0; kk < 8; ++kk) {
        int k0 = kk * 32;
        short8v a = *(const short8v*)&Y[(size_t)arow * 256 + k0 + lg * 8];
#pragma unroll
        for (int n = 0; n < 4; ++n) {
            short8v b = *(const short8v*)&W[(size_t)(n * 16 + lr) * 256 + k0 + lg * 8];
            acc[n] = __builtin_amdgcn_mfma_f32_16x16x32_bf16(a, b, acc[n], 0, 0, 0);
        }
    }
#pragma unroll
    for (int n = 0; n < 4; ++n)
#pragma unroll
        for (int r = 0; r < 4; ++r)
            Ts[w * 16 + lg * 4 + r][n * 16 + lr] = acc[n][r];
    __syncthreads();
    int b = row0 >> 12, l0 = row0 & 4095;
    for (int i = t; i < 4096; i += 256) {
        int c = i >> 6, l = i & 63;
        size_t o = (((size_t)b * 64 + c) << 12) + l0 + l;
        out[o] = x[o] + Ts[l][c] + pob[c];
    }
}

// ---------------------------------------------------------------- launch
extern "C" void kernel_launch(void* const* d_in, const int* in_sizes, int n_in,
                              void* d_out, int out_size, void* d_ws, size_t ws_size,
                              hipStream_t stream)
{
    (void)in_sizes; (void)n_in; (void)out_size; (void)ws_size;
    const float* x          = (const float*)d_in[0];
    const float* proj_w     = (const float*)d_in[1];
    const float* proj_b     = (const float*)d_in[2];
    const float* ln_g       = (const float*)d_in[3];
    const float* ln_b       = (const float*)d_in[4];
    const float* in_proj_w  = (const float*)d_in[5];
    const float* conv_w     = (const float*)d_in[6];
    const float* conv_b     = (const float*)d_in[7];
    const float* x_proj_w   = (const float*)d_in[8];
    const float* dt_proj_w  = (const float*)d_in[9];
    const float* dt_proj_b  = (const float*)d_in[10];
    const float* A_log      = (const float*)d_in[11];
    const float* Dp         = (const float*)d_in[12];
    const float* out_proj_w = (const float*)d_in[13];
    const float* proj_out_w = (const float*)d_in[14];
    const float* proj_out_b = (const float*)d_in[15];
    float* out = (float*)d_out;

    char* wsb = (char*)d_ws;
    __hip_bfloat16* Wt  = (__hip_bfloat16*)(wsb);             // 131072 B
    __hip_bfloat16* W2t = (__hip_bfloat16*)(wsb + 131072);    // 32768 B
    __hip_bfloat16* xmb = (__hip_bfloat16*)(wsb + 163840);    // 4 MB
    float* xz = (float*)(wsb + 4358144);                      // 32 MB
    float* u  = (float*)(wsb + 37912576);                     // 16 MB
    float* dt = (float*)(wsb + 54689792);                     // 16 MB
    float* Bc = (float*)(wsb + 71467008);                     // 1 MB
    float* Cc = (float*)(wsb + 72515584);                     // 1 MB
    float* Pg = (float*)(wsb + 73564160);                     // 4 MB
    float* Sg = (float*)(wsb + 77758464);                     // 4 MB
    float* h0 = (float*)(wsb + 81952768);                     // 4 MB
    __hip_bfloat16* yb = (__hip_bfloat16*)(wsb + 86147072);   // 8 MB

    k_prep<<<80, 256, 0, stream>>>(in_proj_w, out_proj_w, proj_out_w, Wt, W2t);
    k_proj_ln<<<256, 256, 0, stream>>>(x, proj_w, proj_b, ln_g, ln_b, xmb);
    k_gemm_in<<<dim3(4, 128), 256, 0, stream>>>(xmb, Wt, xz);
    k_conv<<<16384, 256, 0, stream>>>(xz, conv_w, conv_b, u);
    k_xproj_dt<<<256, 256, 0, stream>>>(u, x_proj_w, dt_proj_w, dt_proj_b, dt, Bc, Cc);
    k_scan1<<<256, 256, 0, stream>>>(dt, u, Bc, A_log, Pg, Sg);
    k_scan2<<<64, 256, 0, stream>>>(Pg, Sg, h0);
    k_scan3<<<256, 256, 0, stream>>>(dt, u, Bc, Cc, xz, A_log, h0, Dp, yb);
    k_gemm_out<<<256, 256, 0, stream>>>(yb, W2t, proj_out_b, x, out);
}

// Round 3
// 217.505 us; speedup vs baseline: 1.7118x; 1.4932x over previous
//
#include <hip/hip_runtime.h>
#include <hip/hip_bf16.h>
#include <math.h>

#define L_ 4096
#define DM 128
#define DI 256
#define DS 16

typedef __attribute__((ext_vector_type(8))) short short8v;
typedef __attribute__((ext_vector_type(4))) float f32x4;
typedef __hip_bfloat16 bf16;

__device__ __forceinline__ float silu_f(float v) { return v / (1.0f + __expf(-v)); }
__device__ __forceinline__ float bf(bf16 v) { return __bfloat162float(v); }
__device__ __forceinline__ bf16 fb(float v) { return __float2bfloat16(v); }

// ---------------------------------------------------------------- prep: weight repacks
// blk 0..15  : Wt[n][k]  = bf16(in_proj_w[k][n])      (512x128)
// blk 16     : W1t[n][k] = bf16(proj_w[k][n])         (128x64)
// blk 17..80 : W2t[c][r] = bf16(sum_k out_proj_w[r][k]*proj_out_w[k][c])  (64x256)
// blk 81..128: Wxt[n][k] = bf16(x_proj_w[k][n]) n<40 else 0               (48x256)
__global__ __launch_bounds__(256) void k_prep(
    const float* __restrict__ ipw, const float* __restrict__ pw,
    const float* __restrict__ opw, const float* __restrict__ pow_,
    const float* __restrict__ xpw,
    bf16* __restrict__ Wt, bf16* __restrict__ W1t,
    bf16* __restrict__ W2t, bf16* __restrict__ Wxt)
{
    int blk = blockIdx.x, t = threadIdx.x;
    if (blk < 16) {
        for (int it = 0; it < 16; ++it) {
            int e = blk * 4096 + it * 256 + t;
            int n = e >> 7, k = e & 127;
            Wt[e] = fb(ipw[k * 512 + n]);
        }
    } else if (blk == 16) {
        for (int it = 0; it < 32; ++it) {
            int e = it * 256 + t;
            int n = e >> 6, k = e & 63;
            W1t[e] = fb(pw[k * 128 + n]);
        }
    } else if (blk < 81) {
        __shared__ float pls[128][65];
        for (int i = t; i < 8192; i += 256) pls[i >> 6][i & 63] = pow_[i];
        __syncthreads();
        int o = (blk - 17) * 256 + t;
        int c = o >> 8, r = o & 255;
        float acc = 0.f;
        for (int k = 0; k < 128; ++k) acc += opw[r * 128 + k] * pls[k][c];
        W2t[o] = fb(acc);
    } else {
        int e = (blk - 81) * 256 + t;
        int n = e >> 8, k = e & 255;
        Wxt[e] = fb(n < 40 ? xpw[k * 40 + n] : 0.f);
    }
}

// ---------------------------------------------------------------- proj MFMA + LN + in_proj MFMA
// block: 64 rows (b, l0..l0+63). 4 waves.
__global__ __launch_bounds__(256) void k_projln_in(
    const float* __restrict__ x, const bf16* __restrict__ W1t,
    const float* __restrict__ pb, const float* __restrict__ g,
    const float* __restrict__ bta, const bf16* __restrict__ Wt,
    bf16* __restrict__ xzb)
{
    __shared__ bf16 xt[64][72];    // [l][c]
    __shared__ bf16 xm[64][136];   // [l][k]
    int blk = blockIdx.x;
    int b = blk >> 6;
    int l0 = (blk & 63) * 64;
    int t = threadIdx.x;

    // stage + transpose x tile (coalesced global reads)
#pragma unroll
    for (int it = 0; it < 4; ++it) {
        int i = t + it * 256;
        int c = i >> 4, lq = (i & 15) * 4;
        float4 v = *(const float4*)&x[(((size_t)b * 64 + c) << 12) + l0 + lq];
        xt[lq + 0][c] = fb(v.x); xt[lq + 1][c] = fb(v.y);
        xt[lq + 2][c] = fb(v.z); xt[lq + 3][c] = fb(v.w);
    }
    __syncthreads();

    int w = t >> 6, lane = t & 63, lr = lane & 15, lg = lane >> 4;
    const short* xts = (const short*)xt;
    const short* w1 = (const short*)W1t;

    // proj: rows w*16..+15, cols 0..127, K=64
    f32x4 acc1[8] = {};
#pragma unroll
    for (int kk = 0; kk < 2; ++kk) {
        int k0 = kk * 32;
        short8v a = *(const short8v*)&xts[(w * 16 + lr) * 72 + k0 + lg * 8];
#pragma unroll
        for (int n = 0; n < 8; ++n) {
            short8v bb = *(const short8v*)&w1[(n * 16 + lr) * 64 + k0 + lg * 8];
            acc1[n] = __builtin_amdgcn_mfma_f32_16x16x32_bf16(a, bb, acc1[n], 0, 0, 0);
        }
    }
    // bias + LayerNorm (rows = (lg*4+r), cols spread over lr with 8 frags)
    float pbv[8], gv[8], bv[8];
#pragma unroll
    for (int n = 0; n < 8; ++n) {
        int col = n * 16 + lr;
        pbv[n] = pb[col]; gv[n] = g[col]; bv[n] = bta[col];
    }
    float mu[4], inv[4];
#pragma unroll
    for (int r = 0; r < 4; ++r) {
        float s = 0.f;
#pragma unroll
        for (int n = 0; n < 8; ++n) { acc1[n][r] += pbv[n]; s += acc1[n][r]; }
        s += __shfl_xor(s, 1); s += __shfl_xor(s, 2);
        s += __shfl_xor(s, 4); s += __shfl_xor(s, 8);
        mu[r] = s * (1.0f / 128.0f);
        float s2 = 0.f;
#pragma unroll
        for (int n = 0; n < 8; ++n) { float dv = acc1[n][r] - mu[r]; s2 += dv * dv; }
        s2 += __shfl_xor(s2, 1); s2 += __shfl_xor(s2, 2);
        s2 += __shfl_xor(s2, 4); s2 += __shfl_xor(s2, 8);
        inv[r] = rsqrtf(s2 * (1.0f / 128.0f) + 1e-5f);
    }
#pragma unroll
    for (int n = 0; n < 8; ++n)
#pragma unroll
        for (int r = 0; r < 4; ++r)
            xm[w * 16 + lg * 4 + r][n * 16 + lr] =
                fb((acc1[n][r] - mu[r]) * inv[r] * gv[n] + bv[n]);
    __syncthreads();

    // in_proj: rows w*16..+15, cols 0..511, K=128
    const short* xms = (const short*)xm;
    const short* wt = (const short*)Wt;
    f32x4 acc2[32] = {};
#pragma unroll
    for (int kk = 0; kk < 4; ++kk) {
        int k0 = kk * 32;
        short8v a = *(const short8v*)&xms[(w * 16 + lr) * 136 + k0 + lg * 8];
#pragma unroll
        for (int n = 0; n < 32; ++n) {
            short8v bb = *(const short8v*)&wt[(n * 16 + lr) * 128 + k0 + lg * 8];
            acc2[n] = __builtin_amdgcn_mfma_f32_16x16x32_bf16(a, bb, acc2[n], 0, 0, 0);
        }
    }
    size_t rowbase = (size_t)(b * 4096 + l0 + w * 16);
#pragma unroll
    for (int n = 0; n < 32; ++n)
#pragma unroll
        for (int r = 0; r < 4; ++r)
            xzb[(rowbase + lg * 4 + r) * 512 + n * 16 + lr] = fb(acc2[n][r]);
}

// ---------------------------------------------------------------- conv+SiLU + x_proj MFMA + dt + scan pass 1
// block: (b, 64-row chunk). thread t = channel d for the serial phases.
__global__ __launch_bounds__(256) void k_mid(
    const bf16* __restrict__ xzb, const float* __restrict__ cw,
    const float* __restrict__ cb, const bf16* __restrict__ Wxt,
    const float* __restrict__ dtw, const float* __restrict__ dtb,
    const float* __restrict__ A_log,
    bf16* __restrict__ u_g, bf16* __restrict__ dt_g,
    float* __restrict__ Bc, float* __restrict__ Cc,
    float* __restrict__ Sg, float* __restrict__ dts_g)
{
    __shared__ bf16 xs[67][256];   // conv input rows l0-3 .. l0+63
    __shared__ bf16 us[64][264];   // u (padded for MFMA A-frag reads)
    __shared__ float x_s[64][40];  // x_proj output
    int blk = blockIdx.x;
    int b = blk >> 6, ch = blk & 63;
    int l0 = ch * 64;
    int t = threadIdx.x;

    const short* xzs = (const short*)xzb;
    for (int i = t; i < 67 * 32; i += 256) {
        int j = i >> 5, seg = i & 31;
        int gr = l0 - 3 + j;
        short8v v = {0, 0, 0, 0, 0, 0, 0, 0};
        if (gr >= 0)
            v = *(const short8v*)&xzs[((size_t)(b * 4096 + gr)) * 512 + seg * 8];
        *(short8v*)&((short*)xs)[j * 256 + seg * 8] = v;
    }
    __syncthreads();

    // conv + silu
    int d = t;
    float4 wv4 = ((const float4*)cw)[d];
    float cbv = cb[d];
    for (int l = 0; l < 64; ++l) {
        float s = cbv + wv4.x * bf(xs[l][d]) + wv4.y * bf(xs[l + 1][d])
                      + wv4.z * bf(xs[l + 2][d]) + wv4.w * bf(xs[l + 3][d]);
        bf16 ub = fb(silu_f(s));
        us[l][d] = ub;
        u_g[((size_t)(b * 4096 + l0 + l)) * 256 + d] = ub;
    }
    __syncthreads();

    // x_proj: 64x48 (cols 40..47 zero), K=256, MFMA
    int w = t >> 6, lane = t & 63, lr = lane & 15, lg = lane >> 4;
    const short* uss = (const short*)us;
    const short* wx = (const short*)Wxt;
    f32x4 accp[3] = {};
#pragma unroll
    for (int kk = 0; kk < 8; ++kk) {
        int k0 = kk * 32;
        short8v a = *(const short8v*)&uss[(w * 16 + lr) * 264 + k0 + lg * 8];
#pragma unroll
        for (int n = 0; n < 3; ++n) {
            short8v bb = *(const short8v*)&wx[(n * 16 + lr) * 256 + k0 + lg * 8];
            accp[n] = __builtin_amdgcn_mfma_f32_16x16x32_bf16(a, bb, accp[n], 0, 0, 0);
        }
    }
#pragma unroll
    for (int n = 0; n < 3; ++n)
#pragma unroll
        for (int r = 0; r < 4; ++r) {
            int col = n * 16 + lr;
            if (col < 40) x_s[w * 16 + lg * 4 + r][col] = accp[n][r];
        }
    __syncthreads();

    // B, C out
    for (int i = t; i < 1024; i += 256) {
        int l = i >> 4, n = i & 15;
        size_t o = ((size_t)(b * 4096 + l0 + l)) * 16 + n;
        Bc[o] = x_s[l][8 + n];
        Cc[o] = x_s[l][24 + n];
    }

    // dt (softplus) + chunk-local scan summary (S, sum dt)
    float wdt[8];
#pragma unroll
    for (int r = 0; r < 8; ++r) wdt[r] = dtw[r * 256 + d];
    float bias = dtb[d];
    float av[16];
    const float4* Ap = (const float4*)(A_log + d * 16);
#pragma unroll
    for (int j4 = 0; j4 < 4; ++j4) {
        float4 v = Ap[j4];
        av[j4 * 4 + 0] = -__expf(v.x); av[j4 * 4 + 1] = -__expf(v.y);
        av[j4 * 4 + 2] = -__expf(v.z); av[j4 * 4 + 3] = -__expf(v.w);
    }
    float S[16] = {};
    float dts = 0.f;
    for (int l = 0; l < 64; ++l) {
        float sdt = bias;
#pragma unroll
        for (int r = 0; r < 8; ++r) sdt += x_s[l][r] * wdt[r];
        float sp = (sdt > 20.f) ? sdt : log1pf(__expf(sdt));
        bf16 db = fb(sp);
        dt_g[((size_t)(b * 4096 + l0 + l)) * 256 + d] = db;
        float dtv = bf(db);
        float uv = bf(us[l][d]);
        float t1 = dtv * uv;
        dts += dtv;
#pragma unroll
        for (int n = 0; n < 16; ++n)
            S[n] = __expf(av[n] * dtv) * S[n] + t1 * x_s[l][8 + n];
    }
    size_t so = ((size_t)blk * 256 + d) * 16;
#pragma unroll
    for (int n = 0; n < 16; ++n) Sg[so + n] = S[n];
    dts_g[blk * 256 + d] = dts;
}

// ---------------------------------------------------------------- scan over chunks -> h0 per chunk
__global__ __launch_bounds__(256) void k_scan2(
    const float* __restrict__ Sg, const float* __restrict__ dts_g,
    const float* __restrict__ A_log, float* __restrict__ h0)
{
    int blk = blockIdx.x;       // b*16 + dg
    int b = blk >> 4, dg = blk & 15;
    int t = threadIdx.x;
    int dl = t >> 4, n = t & 15;
    int d = dg * 16 + dl;
    float av = -__expf(A_log[d * 16 + n]);
    float h = 0.f;
    for (int cb8 = 0; cb8 < 8; ++cb8) {
        float S8[8], T8[8];
#pragma unroll
        for (int j = 0; j < 8; ++j) {
            int ch = cb8 * 8 + j;
            S8[j] = Sg[((size_t)(b * 64 + ch) * 256 + d) * 16 + n];
            T8[j] = dts_g[(size_t)(b * 64 + ch) * 256 + d];
        }
#pragma unroll
        for (int j = 0; j < 8; ++j) {
            int ch = cb8 * 8 + j;
            h0[((size_t)(b * 64 + ch) * 256 + d) * 16 + n] = h;
            h = __expf(av * T8[j]) * h + S8[j];
        }
    }
}

// ---------------------------------------------------------------- recurrence + gate + out-GEMM + residual (NCHW)
__global__ __launch_bounds__(256) void k_scan3_out(
    const bf16* __restrict__ dt_g, const bf16* __restrict__ u_g,
    const float* __restrict__ Bc, const float* __restrict__ Cc,
    const bf16* __restrict__ xzb, const float* __restrict__ A_log,
    const float* __restrict__ h0, const float* __restrict__ Dp,
    const bf16* __restrict__ W2t, const float* __restrict__ pob,
    const float* __restrict__ x, float* __restrict__ out)
{
    __shared__ float Bs[64][16], Cs[64][16];
    __shared__ bf16 ys[64][264];
    __shared__ float Ts[64][65];
    int blk = blockIdx.x;
    int b = blk >> 6, ch = blk & 63;
    int l0 = ch * 64;
    int t = threadIdx.x;

    for (int i = t; i < 1024; i += 256) {
        int l = i >> 4, n = i & 15;
        size_t o = ((size_t)(b * 4096 + l0 + l)) * 16 + n;
        Bs[l][n] = Bc[o];
        Cs[l][n] = Cc[o];
    }
    __syncthreads();

    int d = t;
    float av[16], h[16];
    const float4* Ap = (const float4*)(A_log + d * 16);
#pragma unroll
    for (int j4 = 0; j4 < 4; ++j4) {
        float4 v = Ap[j4];
        av[j4 * 4 + 0] = -__expf(v.x); av[j4 * 4 + 1] = -__expf(v.y);
        av[j4 * 4 + 2] = -__expf(v.z); av[j4 * 4 + 3] = -__expf(v.w);
    }
    size_t hb = ((size_t)blk * 256 + d) * 16;
#pragma unroll
    for (int n = 0; n < 16; ++n) h[n] = h0[hb + n];
    float Dd = Dp[d];
    for (int l = 0; l < 64; ++l) {
        size_t row = (size_t)(b * 4096 + l0 + l);
        float dtv = bf(dt_g[row * 256 + d]);
        float uv = bf(u_g[row * 256 + d]);
        float zv = bf(xzb[row * 512 + 256 + d]);
        float t1 = dtv * uv;
        float acc = 0.f;
#pragma unroll
        for (int n = 0; n < 16; ++n) {
            h[n] = __expf(av[n] * dtv) * h[n] + t1 * Bs[l][n];
            acc += h[n] * Cs[l][n];
        }
        ys[l][d] = fb((acc + uv * Dd) * silu_f(zv));
    }
    __syncthreads();

    // (y @ W2) : 64 rows x 64 cols, K=256
    int w = t >> 6, lane = t & 63, lr = lane & 15, lg = lane >> 4;
    const short* yss = (const short*)ys;
    const short* w2 = (const short*)W2t;
    f32x4 acc4[4] = {};
#pragma unroll
    for (int kk = 0; kk < 8; ++kk) {
        int k0 = kk * 32;
        short8v a = *(const short8v*)&yss[(w * 16 + lr) * 264 + k0 + lg * 8];
#pragma unroll
        for (int n = 0; n < 4; ++n) {
            short8v bb = *(const short8v*)&w2[(n * 16 + lr) * 256 + k0 + lg * 8];
            acc4[n] = __builtin_amdgcn_mfma_f32_16x16x32_bf16(a, bb, acc4[n], 0, 0, 0);
        }
    }
#pragma unroll
    for (int n = 0; n < 4; ++n)
#pragma unroll
        for (int r = 0; r < 4; ++r)
            Ts[w * 16 + lg * 4 + r][n * 16 + lr] = acc4[n][r];
    __syncthreads();
    for (int i = t; i < 4096; i += 256) {
        int c = i >> 6, l = i & 63;
        size_t o = (((size_t)b * 64 + c) << 12) + l0 + l;
        out[o] = x[o] + Ts[l][c] + pob[c];
    }
}

// ---------------------------------------------------------------- launch
extern "C" void kernel_launch(void* const* d_in, const int* in_sizes, int n_in,
                              void* d_out, int out_size, void* d_ws, size_t ws_size,
                              hipStream_t stream)
{
    (void)in_sizes; (void)n_in; (void)out_size; (void)ws_size;
    const float* x          = (const float*)d_in[0];
    const float* proj_w     = (const float*)d_in[1];
    const float* proj_b     = (const float*)d_in[2];
    const float* ln_g       = (const float*)d_in[3];
    const float* ln_b       = (const float*)d_in[4];
    const float* in_proj_w  = (const float*)d_in[5];
    const float* conv_w     = (const float*)d_in[6];
    const float* conv_b     = (const float*)d_in[7];
    const float* x_proj_w   = (const float*)d_in[8];
    const float* dt_proj_w  = (const float*)d_in[9];
    const float* dt_proj_b  = (const float*)d_in[10];
    const float* A_log      = (const float*)d_in[11];
    const float* Dp         = (const float*)d_in[12];
    const float* out_proj_w = (const float*)d_in[13];
    const float* proj_out_w = (const float*)d_in[14];
    const float* proj_out_b = (const float*)d_in[15];
    float* out = (float*)d_out;

    char* wsb = (char*)d_ws;
    bf16* Wt    = (bf16*)(wsb + 0);         // 131072 B
    bf16* W1t   = (bf16*)(wsb + 131072);    //  16384 B
    bf16* W2t   = (bf16*)(wsb + 147456);    //  32768 B
    bf16* Wxt   = (bf16*)(wsb + 180224);    //  24576 B
    bf16* xzb   = (bf16*)(wsb + 204800);    // 16 MB
    bf16* u_g   = (bf16*)(wsb + 16982016);  //  8 MB
    bf16* dt_g  = (bf16*)(wsb + 25370624);  //  8 MB
    float* Bc   = (float*)(wsb + 33759232); //  1 MB
    float* Cc   = (float*)(wsb + 34807808); //  1 MB
    float* Sg   = (float*)(wsb + 35856384); //  4 MB
    float* dts  = (float*)(wsb + 40050688); // 256 KB
    float* h0   = (float*)(wsb + 40312832); //  4 MB

    k_prep<<<129, 256, 0, stream>>>(in_proj_w, proj_w, out_proj_w, proj_out_w,
                                    x_proj_w, Wt, W1t, W2t, Wxt);
    k_projln_in<<<256, 256, 0, stream>>>(x, W1t, proj_b, ln_g, ln_b, Wt, xzb);
    k_mid<<<256, 256, 0, stream>>>(xzb, conv_w, conv_b, Wxt, dt_proj_w, dt_proj_b,
                                   A_log, u_g, dt_g, Bc, Cc, Sg, dts);
    k_scan2<<<64, 256, 0, stream>>>(Sg, dts, A_log, h0);
    k_scan3_out<<<256, 256, 0, stream>>>(dt_g, u_g, Bc, Cc, xzb, A_log, h0, Dp,
                                         W2t, proj_out_b, x, out);
}

// Round 4
// 181.724 us; speedup vs baseline: 2.0489x; 1.1969x over previous
//
#include <hip/hip_runtime.h>
#include <hip/hip_bf16.h>
#include <math.h>

#define L_ 4096
#define DM 128
#define DI 256
#define DS 16
#define CH 32          // scan chunk length
#define NCH 128        // chunks per batch (L_/CH)

typedef __attribute__((ext_vector_type(8))) short short8v;
typedef __attribute__((ext_vector_type(4))) float f32x4;
typedef __hip_bfloat16 bf16;

__device__ __forceinline__ float silu_f(float v) { return v / (1.0f + __expf(-v)); }
__device__ __forceinline__ float bf(bf16 v) { return __bfloat162float(v); }
__device__ __forceinline__ bf16 fb(float v) { return __float2bfloat16(v); }
__device__ __forceinline__ unsigned short bfbits(float v) {
    bf16 b = fb(v); return *(unsigned short*)&b;
}
__device__ __forceinline__ float frombits(unsigned int u) {
    unsigned short s = (unsigned short)u; bf16 b; *(unsigned short*)&b = s; return bf(b);
}

// ---------------------------------------------------------------- prep: weight repacks
// blk 0..15  : Wt[n][k]  = bf16(in_proj_w[k][n])      (512x128)
// blk 16     : W1t[n][k] = bf16(proj_w[k][n])         (128x64)
// blk 17..80 : W2t[c][r] = bf16(sum_k out_proj_w[r][k]*proj_out_w[k][c])  (64x256)
// blk 81..128: Wxt[n][k] = bf16(x_proj_w[k][n]) n<40 else 0               (48x256)
__global__ __launch_bounds__(256) void k_prep(
    const float* __restrict__ ipw, const float* __restrict__ pw,
    const float* __restrict__ opw, const float* __restrict__ pow_,
    const float* __restrict__ xpw,
    bf16* __restrict__ Wt, bf16* __restrict__ W1t,
    bf16* __restrict__ W2t, bf16* __restrict__ Wxt)
{
    int blk = blockIdx.x, t = threadIdx.x;
    if (blk < 16) {
        for (int it = 0; it < 16; ++it) {
            int e = blk * 4096 + it * 256 + t;
            int n = e >> 7, k = e & 127;
            Wt[e] = fb(ipw[k * 512 + n]);
        }
    } else if (blk == 16) {
        for (int it = 0; it < 32; ++it) {
            int e = it * 256 + t;
            int n = e >> 6, k = e & 63;
            W1t[e] = fb(pw[k * 128 + n]);
        }
    } else if (blk < 81) {
        __shared__ float pls[128][65];
        for (int i = t; i < 8192; i += 256) pls[i >> 6][i & 63] = pow_[i];
        __syncthreads();
        int o = (blk - 17) * 256 + t;
        int c = o >> 8, r = o & 255;
        float acc = 0.f;
        for (int k = 0; k < 128; ++k) acc += opw[r * 128 + k] * pls[k][c];
        W2t[o] = fb(acc);
    } else {
        int e = (blk - 81) * 256 + t;
        int n = e >> 8, k = e & 255;
        Wxt[e] = fb(n < 40 ? xpw[k * 40 + n] : 0.f);
    }
}

// ---------------------------------------------------------------- proj MFMA + LN + in_proj MFMA
// block: 64 rows. 4 waves. in_proj cols split across waves (128 cols each).
__global__ __launch_bounds__(256) void k_projln_in(
    const float* __restrict__ x, const bf16* __restrict__ W1t,
    const float* __restrict__ pb, const float* __restrict__ g,
    const float* __restrict__ bta, const bf16* __restrict__ Wt,
    bf16* __restrict__ xzb)
{
    __shared__ bf16 xt[64][72];    // [l][c]
    __shared__ bf16 xm[64][136];   // [l][k]
    int blk = blockIdx.x;
    int b = blk >> 6;
    int l0 = (blk & 63) * 64;
    int t = threadIdx.x;

#pragma unroll
    for (int it = 0; it < 4; ++it) {
        int i = t + it * 256;
        int c = i >> 4, lq = (i & 15) * 4;
        float4 v = *(const float4*)&x[(((size_t)b * 64 + c) << 12) + l0 + lq];
        xt[lq + 0][c] = fb(v.x); xt[lq + 1][c] = fb(v.y);
        xt[lq + 2][c] = fb(v.z); xt[lq + 3][c] = fb(v.w);
    }
    __syncthreads();

    int w = t >> 6, lane = t & 63, lr = lane & 15, lg = lane >> 4;
    const short* xts = (const short*)xt;
    const short* w1 = (const short*)W1t;

    // proj: wave w -> rows w*16..+15, cols 0..127, K=64
    f32x4 acc1[8] = {};
#pragma unroll
    for (int kk = 0; kk < 2; ++kk) {
        int k0 = kk * 32;
        short8v a = *(const short8v*)&xts[(w * 16 + lr) * 72 + k0 + lg * 8];
#pragma unroll
        for (int n = 0; n < 8; ++n) {
            short8v bb = *(const short8v*)&w1[(n * 16 + lr) * 64 + k0 + lg * 8];
            acc1[n] = __builtin_amdgcn_mfma_f32_16x16x32_bf16(a, bb, acc1[n], 0, 0, 0);
        }
    }
    float pbv[8], gv[8], bv[8];
#pragma unroll
    for (int n = 0; n < 8; ++n) {
        int col = n * 16 + lr;
        pbv[n] = pb[col]; gv[n] = g[col]; bv[n] = bta[col];
    }
    float mu[4], inv[4];
#pragma unroll
    for (int r = 0; r < 4; ++r) {
        float s = 0.f;
#pragma unroll
        for (int n = 0; n < 8; ++n) { acc1[n][r] += pbv[n]; s += acc1[n][r]; }
        s += __shfl_xor(s, 1); s += __shfl_xor(s, 2);
        s += __shfl_xor(s, 4); s += __shfl_xor(s, 8);
        mu[r] = s * (1.0f / 128.0f);
        float s2 = 0.f;
#pragma unroll
        for (int n = 0; n < 8; ++n) { float dv = acc1[n][r] - mu[r]; s2 += dv * dv; }
        s2 += __shfl_xor(s2, 1); s2 += __shfl_xor(s2, 2);
        s2 += __shfl_xor(s2, 4); s2 += __shfl_xor(s2, 8);
        inv[r] = rsqrtf(s2 * (1.0f / 128.0f) + 1e-5f);
    }
#pragma unroll
    for (int n = 0; n < 8; ++n)
#pragma unroll
        for (int r = 0; r < 4; ++r)
            xm[w * 16 + lg * 4 + r][n * 16 + lr] =
                fb((acc1[n][r] - mu[r]) * inv[r] * gv[n] + bv[n]);
    __syncthreads();

    // in_proj: wave w -> cols w*128..+127, rows 0..63, K=128
    const short* xms = (const short*)xm;
    const short* wt = (const short*)Wt;
    f32x4 acc2[4][8] = {};
#pragma unroll
    for (int kk = 0; kk < 4; ++kk) {
        int k0 = kk * 32;
        short8v a[4];
#pragma unroll
        for (int m = 0; m < 4; ++m)
            a[m] = *(const short8v*)&xms[(m * 16 + lr) * 136 + k0 + lg * 8];
#pragma unroll
        for (int n = 0; n < 8; ++n) {
            short8v bb = *(const short8v*)&wt[((w * 8 + n) * 16 + lr) * 128 + k0 + lg * 8];
#pragma unroll
            for (int m = 0; m < 4; ++m)
                acc2[m][n] = __builtin_amdgcn_mfma_f32_16x16x32_bf16(a[m], bb, acc2[m][n], 0, 0, 0);
        }
    }
    size_t rowbase = (size_t)(b * 4096 + l0);
#pragma unroll
    for (int m = 0; m < 4; ++m)
#pragma unroll
        for (int n = 0; n < 8; ++n)
#pragma unroll
            for (int r = 0; r < 4; ++r)
                xzb[(rowbase + m * 16 + lg * 4 + r) * 512 + w * 128 + n * 16 + lr]
                    = fb(acc2[m][n][r]);
}

// ---------------------------------------------------------------- conv+SiLU + x_proj MFMA + dt + scan pass 1
// block: (b, 32-row chunk). 512 blocks.
__global__ __launch_bounds__(256) void k_mid(
    const bf16* __restrict__ xzb, const float* __restrict__ cw,
    const float* __restrict__ cb, const bf16* __restrict__ Wxt,
    const float* __restrict__ dtw, const float* __restrict__ dtb,
    const float* __restrict__ A_log,
    unsigned int* __restrict__ ud_g,
    float* __restrict__ Bc, float* __restrict__ Cc,
    float* __restrict__ Sg, float* __restrict__ dts_g)
{
    __shared__ bf16 xs[35][256];   // conv input rows l0-3 .. l0+31
    __shared__ bf16 us[32][264];   // u (padded for MFMA A-frag reads)
    __shared__ float x_s[32][40];  // x_proj output
    int blk = blockIdx.x;
    int b = blk >> 7, ch = blk & 127;
    int l0 = ch * CH;
    int t = threadIdx.x;

    const short* xzs = (const short*)xzb;
    for (int i = t; i < 35 * 32; i += 256) {
        int j = i >> 5, seg = i & 31;
        int gr = l0 - 3 + j;
        short8v v = {0, 0, 0, 0, 0, 0, 0, 0};
        if (gr >= 0)
            v = *(const short8v*)&xzs[((size_t)(b * 4096 + gr)) * 512 + seg * 8];
        *(short8v*)&((short*)xs)[j * 256 + seg * 8] = v;
    }
    __syncthreads();

    // conv + silu (rolling window, 1 LDS read per step)
    int d = t;
    float4 wv4 = ((const float4*)cw)[d];
    float cbv = cb[d];
    float x0 = bf(xs[0][d]), x1 = bf(xs[1][d]), x2 = bf(xs[2][d]);
    for (int l = 0; l < CH; ++l) {
        float x3 = bf(xs[l + 3][d]);
        float s = cbv + wv4.x * x0 + wv4.y * x1 + wv4.z * x2 + wv4.w * x3;
        us[l][d] = fb(silu_f(s));
        x0 = x1; x1 = x2; x2 = x3;
    }
    __syncthreads();

    // x_proj: 32x48, K=256, MFMA (waves 0,1 only)
    int w = t >> 6, lane = t & 63, lr = lane & 15, lg = lane >> 4;
    if (w < 2) {
        const short* uss = (const short*)us;
        const short* wx = (const short*)Wxt;
        f32x4 accp[3] = {};
#pragma unroll
        for (int kk = 0; kk < 8; ++kk) {
            int k0 = kk * 32;
            short8v a = *(const short8v*)&uss[(w * 16 + lr) * 264 + k0 + lg * 8];
#pragma unroll
            for (int n = 0; n < 3; ++n) {
                short8v bb = *(const short8v*)&wx[(n * 16 + lr) * 256 + k0 + lg * 8];
                accp[n] = __builtin_amdgcn_mfma_f32_16x16x32_bf16(a, bb, accp[n], 0, 0, 0);
            }
        }
#pragma unroll
        for (int n = 0; n < 3; ++n)
#pragma unroll
            for (int r = 0; r < 4; ++r) {
                int col = n * 16 + lr;
                if (col < 40) x_s[w * 16 + lg * 4 + r][col] = accp[n][r];
            }
    }
    __syncthreads();

    // B, C out
    for (int i = t; i < CH * 16; i += 256) {
        int l = i >> 4, n = i & 15;
        size_t o = ((size_t)(b * 4096 + l0 + l)) * 16 + n;
        Bc[o] = x_s[l][8 + n];
        Cc[o] = x_s[l][24 + n];
    }

    // dt (softplus) + pack (u,dt) + chunk-local scan summary
    float wdt[8];
#pragma unroll
    for (int r = 0; r < 8; ++r) wdt[r] = dtw[r * 256 + d];
    float bias = dtb[d];
    float av[16];
    const float4* Ap = (const float4*)(A_log + d * 16);
#pragma unroll
    for (int j4 = 0; j4 < 4; ++j4) {
        float4 v = Ap[j4];
        av[j4 * 4 + 0] = -__expf(v.x); av[j4 * 4 + 1] = -__expf(v.y);
        av[j4 * 4 + 2] = -__expf(v.z); av[j4 * 4 + 3] = -__expf(v.w);
    }
    float S[16] = {};
    float dts = 0.f;
    for (int l = 0; l < CH; ++l) {
        float sdt = bias;
#pragma unroll
        for (int r = 0; r < 8; ++r) sdt += x_s[l][r] * wdt[r];
        float sp = (sdt > 20.f) ? sdt : log1pf(__expf(sdt));
        unsigned short dtb16 = bfbits(sp);
        float dtv = frombits(dtb16);
        float uv = bf(us[l][d]);
        ud_g[((size_t)(b * 4096 + l0 + l)) * 256 + d] =
            ((unsigned int)dtb16 << 16) | (unsigned int)bfbits(uv);
        float t1 = dtv * uv;
        dts += dtv;
#pragma unroll
        for (int n = 0; n < 16; ++n)
            S[n] = __expf(av[n] * dtv) * S[n] + t1 * x_s[l][8 + n];
    }
    size_t so = ((size_t)blk * 256 + d) * 16;
#pragma unroll
    for (int n = 0; n < 16; ++n) Sg[so + n] = S[n];
    dts_g[(size_t)blk * 256 + d] = dts;
}

// ---------------------------------------------------------------- scan over chunks -> h0 per chunk
__global__ __launch_bounds__(256) void k_scan2(
    const float* __restrict__ Sg, const float* __restrict__ dts_g,
    const float* __restrict__ A_log, float* __restrict__ h0)
{
    int blk = blockIdx.x;       // b*16 + dg
    int b = blk >> 4, dg = blk & 15;
    int t = threadIdx.x;
    int dl = t >> 4, n = t & 15;
    int d = dg * 16 + dl;
    float av = -__expf(A_log[d * 16 + n]);
    float h = 0.f;
    for (int c8 = 0; c8 < NCH / 8; ++c8) {
        float S8[8], T8[8];
#pragma unroll
        for (int j = 0; j < 8; ++j) {
            int ch = c8 * 8 + j;
            S8[j] = Sg[((size_t)(b * NCH + ch) * 256 + d) * 16 + n];
            T8[j] = dts_g[(size_t)(b * NCH + ch) * 256 + d];
        }
#pragma unroll
        for (int j = 0; j < 8; ++j) {
            int ch = c8 * 8 + j;
            h0[((size_t)(b * NCH + ch) * 256 + d) * 16 + n] = h;
            h = __expf(av * T8[j]) * h + S8[j];
        }
    }
}

// ---------------------------------------------------------------- recurrence + gate + out-GEMM + residual (NCHW)
// block: (b, 32-row chunk). 512 blocks.
__global__ __launch_bounds__(256) void k_scan3_out(
    const unsigned int* __restrict__ ud_g,
    const float* __restrict__ Bc, const float* __restrict__ Cc,
    const bf16* __restrict__ xzb, const float* __restrict__ A_log,
    const float* __restrict__ h0, const float* __restrict__ Dp,
    const bf16* __restrict__ W2t, const float* __restrict__ pob,
    const float* __restrict__ x, float* __restrict__ out)
{
    __shared__ float Bs[32][16], Cs[32][16];
    __shared__ bf16 ys[32][264];
    __shared__ float Ts[32][65];
    int blk = blockIdx.x;
    int b = blk >> 7, ch = blk & 127;
    int l0 = ch * CH;
    int t = threadIdx.x;

    for (int i = t; i < CH * 16; i += 256) {
        int l = i >> 4, n = i & 15;
        size_t o = ((size_t)(b * 4096 + l0 + l)) * 16 + n;
        Bs[l][n] = Bc[o];
        Cs[l][n] = Cc[o];
    }
    __syncthreads();

    int d = t;
    float av[16], h[16];
    const float4* Ap = (const float4*)(A_log + d * 16);
#pragma unroll
    for (int j4 = 0; j4 < 4; ++j4) {
        float4 v = Ap[j4];
        av[j4 * 4 + 0] = -__expf(v.x); av[j4 * 4 + 1] = -__expf(v.y);
        av[j4 * 4 + 2] = -__expf(v.z); av[j4 * 4 + 3] = -__expf(v.w);
    }
    size_t hb = ((size_t)blk * 256 + d) * 16;
#pragma unroll
    for (int n = 0; n < 16; ++n) h[n] = h0[hb + n];
    float Dd = Dp[d];
    for (int l = 0; l < CH; ++l) {
        size_t row = (size_t)(b * 4096 + l0 + l);
        unsigned int p = ud_g[row * 256 + d];
        float uv = frombits(p & 0xffffu);
        float dtv = frombits(p >> 16);
        float zv = bf(xzb[row * 512 + 256 + d]);
        float t1 = dtv * uv;
        float acc = 0.f;
#pragma unroll
        for (int n = 0; n < 16; ++n) {
            h[n] = __expf(av[n] * dtv) * h[n] + t1 * Bs[l][n];
            acc += h[n] * Cs[l][n];
        }
        ys[l][d] = fb((acc + uv * Dd) * silu_f(zv));
    }
    __syncthreads();

    // (y @ W2): 32 rows x 64 cols, K=256. wave w: rows (w&1)*16, cols (w>>1)*32.
    int w = t >> 6, lane = t & 63, lr = lane & 15, lg = lane >> 4;
    int wr = w & 1, wc = w >> 1;
    const short* yss = (const short*)ys;
    const short* w2 = (const short*)W2t;
    f32x4 acc4[2] = {};
#pragma unroll
    for (int kk = 0; kk < 8; ++kk) {
        int k0 = kk * 32;
        short8v a = *(const short8v*)&yss[(wr * 16 + lr) * 264 + k0 + lg * 8];
#pragma unroll
        for (int n = 0; n < 2; ++n) {
            short8v bb = *(const short8v*)&w2[((wc * 2 + n) * 16 + lr) * 256 + k0 + lg * 8];
            acc4[n] = __builtin_amdgcn_mfma_f32_16x16x32_bf16(a, bb, acc4[n], 0, 0, 0);
        }
    }
#pragma unroll
    for (int n = 0; n < 2; ++n)
#pragma unroll
        for (int r = 0; r < 4; ++r)
            Ts[wr * 16 + lg * 4 + r][wc * 32 + n * 16 + lr] = acc4[n][r];
    __syncthreads();
    for (int i = t; i < 64 * CH; i += 256) {
        int c = i >> 5, l = i & 31;
        size_t o = (((size_t)b * 64 + c) << 12) + l0 + l;
        out[o] = x[o] + Ts[l][c] + pob[c];
    }
}

// ---------------------------------------------------------------- launch
extern "C" void kernel_launch(void* const* d_in, const int* in_sizes, int n_in,
                              void* d_out, int out_size, void* d_ws, size_t ws_size,
                              hipStream_t stream)
{
    (void)in_sizes; (void)n_in; (void)out_size; (void)ws_size;
    const float* x          = (const float*)d_in[0];
    const float* proj_w     = (const float*)d_in[1];
    const float* proj_b     = (const float*)d_in[2];
    const float* ln_g       = (const float*)d_in[3];
    const float* ln_b       = (const float*)d_in[4];
    const float* in_proj_w  = (const float*)d_in[5];
    const float* conv_w     = (const float*)d_in[6];
    const float* conv_b     = (const float*)d_in[7];
    const float* x_proj_w   = (const float*)d_in[8];
    const float* dt_proj_w  = (const float*)d_in[9];
    const float* dt_proj_b  = (const float*)d_in[10];
    const float* A_log      = (const float*)d_in[11];
    const float* Dp         = (const float*)d_in[12];
    const float* out_proj_w = (const float*)d_in[13];
    const float* proj_out_w = (const float*)d_in[14];
    const float* proj_out_b = (const float*)d_in[15];
    float* out = (float*)d_out;

    char* wsb = (char*)d_ws;
    bf16* Wt    = (bf16*)(wsb + 0);          // 131072 B
    bf16* W1t   = (bf16*)(wsb + 131072);     //  16384 B
    bf16* W2t   = (bf16*)(wsb + 147456);     //  32768 B
    bf16* Wxt   = (bf16*)(wsb + 180224);     //  24576 B
    bf16* xzb   = (bf16*)(wsb + 204800);     // 16 MB
    unsigned int* ud_g = (unsigned int*)(wsb + 16982016);  // 16 MB
    float* Bc   = (float*)(wsb + 33759232);  //  1 MB
    float* Cc   = (float*)(wsb + 34807808);  //  1 MB
    float* Sg   = (float*)(wsb + 35856384);  //  8 MB
    float* dts  = (float*)(wsb + 44244992);  // 512 KB
    float* h0   = (float*)(wsb + 44769280);  //  8 MB

    k_prep<<<129, 256, 0, stream>>>(in_proj_w, proj_w, out_proj_w, proj_out_w,
                                    x_proj_w, Wt, W1t, W2t, Wxt);
    k_projln_in<<<256, 256, 0, stream>>>(x, W1t, proj_b, ln_g, ln_b, Wt, xzb);
    k_mid<<<512, 256, 0, stream>>>(xzb, conv_w, conv_b, Wxt, dt_proj_w, dt_proj_b,
                                   A_log, ud_g, Bc, Cc, Sg, dts);
    k_scan2<<<64, 256, 0, stream>>>(Sg, dts, A_log, h0);
    k_scan3_out<<<512, 256, 0, stream>>>(ud_g, Bc, Cc, xzb, A_log, h0, Dp,
                                         W2t, proj_out_b, x, out);
}